// Round 5
// baseline (4757.265 us; speedup 1.0000x reference)
//
#include <hip/hip_runtime.h>
#include <stdint.h>

// S=64, B=64, C=H=E=512, V=32000, steps T=48
// ONE persistent kernel (224 WGs, NORMAL launch - co-residency guaranteed by
// __launch_bounds__(256,1) => >=1 block/CU => 224 <= 256 always resident;
// no grid-sync is used, only flag handshakes):
//   Group A (WG 0-31):   P0: gru0 -> h1 (bf16) + split-K q-partials, then attention b=wg
//   Group B (WG 32-63):  gh1 in registers, then P3: gi1+combine -> h_bf + h2bf[t]
//   Group C (WG 64-95):  attention for b=32..63
//   Group V-L (96-127):  per step: tl(t) = tanh(h2bf[t]@Whid2out^T + b) -> tl_f, tl_bf
//   Group V-G (128-223): per step: sumexp partials; 125 vocab chunks (256 rows)
//                        strided by 96 (prologue: convert own chunks fp32->bf16)
// Sync: scattered per-WG token slots; recurrence polls s_sleep(1), V polls s_sleep(16).
// V groups are pure consumers -> no new edges into the recurrence sync graph.
// h2bf/tl_bf/tl_f are zero-initialized as insurance (any V failure => finite error).

using bf16x8 = __attribute__((ext_vector_type(8))) short;
using f32x4  = __attribute__((ext_vector_type(4))) float;
using s16x4  = __attribute__((ext_vector_type(4))) short;
typedef unsigned long long u64;
typedef unsigned int u32;

#define DI __device__ __forceinline__

DI short f2bf(float x){
  union { float f; uint32_t u; } v; v.f = x;
  uint32_t r = (v.u + 0x7FFFu + ((v.u >> 16) & 1u)) >> 16;
  return (short)r;
}
DI float bf2f(short s){
  union { uint32_t u; float f; } v; v.u = ((uint32_t)(unsigned short)s) << 16; return v.f;
}
DI float sigm(float x){ return __fdividef(1.f, 1.f + __expf(-x)); }
DI float ftanh(float x){ return 1.f - __fdividef(2.f, __expf(2.f*x) + 1.f); }
DI float wsum(float v){
  #pragma unroll
  for (int m = 32; m > 0; m >>= 1) v += __shfl_xor(v, m, 64);
  return v;
}
DI f32x4 mfma16(bf16x8 a, bf16x8 b, f32x4 c){
  return __builtin_amdgcn_mfma_f32_16x16x32_bf16(a, b, c, 0, 0, 0);
}

// AGENT-scope atomics (reach/observe coherence point; no local stale copies)
DI u32  ald32(const u32* p){ return __hip_atomic_load(p, __ATOMIC_RELAXED, __HIP_MEMORY_SCOPE_AGENT); }
DI void ast32(u32* p, u32 v){ __hip_atomic_store(p, v, __ATOMIC_RELAXED, __HIP_MEMORY_SCOPE_AGENT); }
DI u64  ald64(const u64* p){ return __hip_atomic_load(p, __ATOMIC_RELAXED, __HIP_MEMORY_SCOPE_AGENT); }
DI void ast64(u64* p, u64 v){ __hip_atomic_store(p, v, __ATOMIC_RELAXED, __HIP_MEMORY_SCOPE_AGENT); }
DI float aldf(const float* p){ return __hip_atomic_load(p, __ATOMIC_RELAXED, __HIP_MEMORY_SCOPE_AGENT); }
DI void astf(float* p, float v){ __hip_atomic_store(p, v, __ATOMIC_RELAXED, __HIP_MEMORY_SCOPE_AGENT); }

// plain bf16 weight fragment (row-major [N][512])
DI bf16x8 ldb(const short* __restrict__ W, int n0, int k0, int lane){
  return *(const bf16x8*)(W + (size_t)(n0 + (lane & 15)) * 512 + k0 + ((lane >> 4) << 3));
}
// agent-scope bf16 fragment (cross-XCD payloads: h2bf, tl_bf)
DI bf16x8 ldb_ald(const unsigned short* W, int n0, int k0, int lane){
  const u64* p = (const u64*)(W + (size_t)(n0 + (lane & 15)) * 512 + k0 + ((lane >> 4) << 3));
  union { u64 u[2]; bf16x8 f; } cv;
  cv.u[0] = ald64(p); cv.u[1] = ald64(p + 1);
  return cv.f;
}

#define SLOT 64   // dwords per token slot (256 B padding)

// signal: call AFTER __syncthreads() (compiler drains vmcnt before s_barrier)
DI void sig(u32* arr, int slot, u32 tok){
  if (threadIdx.x == 0){
    __builtin_amdgcn_s_waitcnt(0);
    ast32(arr + slot * SLOT, tok);
  }
}
// wait: lane i (<cnt) polls slot base+i; all-ballot; then block barrier
template<int SLP>
DI void waitslots(const u32* arr, int base, int cnt, u32 tok){
  if (threadIdx.x < 64){
    for (;;){
      u32 v = (threadIdx.x < cnt) ? ald32(arr + (base + threadIdx.x) * SLOT) : tok;
      if (__all((int)(v - tok) >= 0)) break;
      __builtin_amdgcn_s_sleep(SLP);
    }
  }
  __syncthreads();
}

// ---------------- elementwise / prep kernels ----------------

struct CvtJobs { const float* src[8]; short* dst[8]; int cum4[9]; };

__global__ __launch_bounds__(256) void k_cvt_multi(CvtJobs jb, int total4){
  int i = blockIdx.x * 256 + threadIdx.x;
  if (i >= total4) return;
  int j = 0;
  #pragma unroll
  for (int k = 0; k < 8; ++k) if (i >= jb.cum4[k + 1]) j = k + 1;
  int off = i - jb.cum4[j];
  float4 v = ((const float4*)jb.src[j])[off];
  s16x4 o; o[0] = f2bf(v.x); o[1] = f2bf(v.y); o[2] = f2bf(v.z); o[3] = f2bf(v.w);
  ((s16x4*)jb.dst[j])[off] = o;
}

__global__ __launch_bounds__(256) void k_tc(const float* __restrict__ W, short* __restrict__ WT){
  int i = blockIdx.x * 256 + threadIdx.x;
  int c = i >> 9, h = i & 511;
  WT[i] = f2bf(W[h * 512 + c]);
}

__global__ __launch_bounds__(256) void k_zero(float* __restrict__ p, int n){
  int i = blockIdx.x * 256 + threadIdx.x;
  if (i < n) p[i] = 0.f;
}

__global__ __launch_bounds__(256) void k_meanmix(const float* __restrict__ ctx, const float* __restrict__ mask,
                                                 const float* __restrict__ txt, float* __restrict__ mixed){
  int i = blockIdx.x * 256 + threadIdx.x;
  int b = i >> 9, c = i & 511;
  float s = 0.f;
  for (int t = 0; t < 64; ++t) s += ctx[(size_t)(t * 64 + b) * 512 + c];
  float dn = 0.f;
  for (int t = 0; t < 64; ++t) dn += mask[t * 64 + b];
  mixed[i] = 0.5f * (s / dn) + 0.5f * txt[i];
}

// pack h0 fp32 -> bf16 packed
__global__ __launch_bounds__(256) void k_pack_h0(const float* __restrict__ h0, u32* __restrict__ hbf){
  int i = blockIdx.x * 256 + threadIdx.x;   // 0..16383
  u32 lo = (u32)(unsigned short)f2bf(h0[2 * i]);
  u32 hi = (u32)(unsigned short)f2bf(h0[2 * i + 1]);
  hbf[i] = lo | (hi << 16);
}

// ---------------- generic wave-tile GEMMs (K = 512, fp32 A) ----------------

DI bf16x8 load_a32(const float* __restrict__ A, int ld, int m0, int k0, int lane){
  const float* p = A + (size_t)(m0 + (lane & 15)) * ld + k0 + ((lane >> 4) << 3);
  bf16x8 f;
  #pragma unroll
  for (int j = 0; j < 8; ++j) f[j] = f2bf(p[j]);
  return f;
}

__global__ __launch_bounds__(256) void k_gemm_bt(const float* __restrict__ A, const short* __restrict__ W,
                                                 float* __restrict__ C, int N, int act){
  int wg = blockIdx.x * 4 + (threadIdx.x >> 6);
  int lane = threadIdx.x & 63;
  int ntiles = N >> 4;
  int mt = wg / ntiles, nt = wg - mt * ntiles;
  int m0 = mt << 4, n0 = nt << 4;
  f32x4 acc = {0.f, 0.f, 0.f, 0.f};
  for (int k = 0; k < 512; k += 32)
    acc = mfma16(load_a32(A, 512, m0, k, lane), ldb(W, n0, k, lane), acc);
  int col = n0 + (lane & 15);
  int r0 = m0 + ((lane >> 4) << 2);
  #pragma unroll
  for (int r = 0; r < 4; ++r){
    float v = acc[r];
    if (act) v = ftanh(v);
    C[(size_t)(r0 + r) * N + col] = v;
  }
}

__global__ __launch_bounds__(256) void k_gemm_bt_obf(const float* __restrict__ A, const short* __restrict__ W,
                                                     short* __restrict__ C, int N){
  int wg = blockIdx.x * 4 + (threadIdx.x >> 6);
  int lane = threadIdx.x & 63;
  int ntiles = N >> 4;
  int mt = wg / ntiles, nt = wg - mt * ntiles;
  int m0 = mt << 4, n0 = nt << 4;
  f32x4 acc = {0.f, 0.f, 0.f, 0.f};
  for (int k = 0; k < 512; k += 32)
    acc = mfma16(load_a32(A, 512, m0, k, lane), ldb(W, n0, k, lane), acc);
  int col = n0 + (lane & 15);
  int r0 = m0 + ((lane >> 4) << 2);
  #pragma unroll
  for (int r = 0; r < 4; ++r)
    C[(size_t)(r0 + r) * N + col] = f2bf(acc[r]);
}

__global__ __launch_bounds__(256) void k_gi0(const int* __restrict__ y, const float* __restrict__ emb,
                                             const short* __restrict__ W, const float* __restrict__ bias,
                                             float* __restrict__ C){
  int wg = blockIdx.x * 4 + (threadIdx.x >> 6);
  int lane = threadIdx.x & 63;
  int mt = wg / 96, nt = wg - mt * 96;
  int m0 = mt << 4, n0 = nt << 4;
  int yr = y[m0 + (lane & 15)];
  const float* arow = emb + (size_t)yr * 512;
  f32x4 acc = {0.f, 0.f, 0.f, 0.f};
  for (int k = 0; k < 512; k += 32){
    const float* p = arow + k + ((lane >> 4) << 3);
    bf16x8 a;
    #pragma unroll
    for (int j = 0; j < 8; ++j) a[j] = f2bf(p[j]);
    acc = mfma16(a, ldb(W, n0, k, lane), acc);
  }
  int col = n0 + (lane & 15);
  int r0 = m0 + ((lane >> 4) << 2);
  #pragma unroll
  for (int r = 0; r < 4; ++r)
    C[(size_t)(r0 + r) * 1536 + col] = acc[r] + bias[col];
}

// ---------------- persistent kernel ----------------

struct RB {
  const float* gi0;        // [48][64][1536] fp32 (incl b_ih0)
  const short* Whh0; const float* bhh0;
  const short* Whid2ctx;   // bf16 [512][512]
  const short* Whh1; const float* bhh1;
  const short* Wcomb; const float* bih1;
  const short* ctx_proj;   // bf16 [s*64+b][512]
  const float* ctx;        // fp32 [s*64+b][512]
  const float* mask;       // [64][64] (s,b)
  const float* wmlp;       // [512]
  unsigned short* h_bf;    // [64][512] bf16 (recurrent state)
  unsigned short* h1_bf;   // [64][512] bf16
  unsigned short* catt_bf; // [64][512] bf16
  float* qpart;            // [8 cg][64 b][512] fp32 split-K q partials
  unsigned short* h2bf;    // [48][64][512] bf16 (for V-L)
  // vocab pipeline
  const short* Whid2out; const float* bh2o;
  const float* o2p_src;    // fp32 [32000][512]
  short* o2p_bf;           // bf16 [32000][512] (converted in-kernel by V-G)
  const float* bop;        // [32000]
  unsigned short* tl_bf;   // [48*64][512] bf16
  float* tl_f;             // [48*64][512] fp32
  float* sumexp;           // [3072]
  u32* barA; u32* barC; u32* barD; u32* barE;  // token slots, stride SLOT
};

__global__ __launch_bounds__(256, 1) void k_recur(RB a){
  // sH/sOut (GEMM phases) and pl (attention score partials) overlay the same LDS.
  __shared__ char smem[16 * 520 * 2 + 16 * 64 * 4];
  unsigned short* sH = (unsigned short*)smem;            // [16][520] bf16 burst tile
  float* sOut = (float*)(smem + 16 * 520 * 2);           // [16][64]
  float* pl   = (float*)smem;                            // [64][65] score partials
  __shared__ float qs[512];
  __shared__ float al[64];
  const int wg = blockIdx.x, tid = threadIdx.x;
  const int wv = tid >> 6, lane = tid & 63;

  // burst 16 rows x 512 bf16 into sH
  auto burst16 = [&](const unsigned short* src, int row0){
    #pragma unroll
    for (int i = 0; i < 8; ++i){
      int idx = tid + i * 256;              // 0..2047
      int r = idx >> 7, c4 = idx & 127;     // 128 b64-chunks per row
      u64 v = ald64((const u64*)(src + (size_t)(row0 + r) * 512) + c4);
      *(u64*)(sH + r * 520 + c4 * 4) = v;
    }
    __syncthreads();
  };
  auto afrag = [&](int k0) -> bf16x8 {
    return *(const bf16x8*)(sH + (lane & 15) * 520 + k0 + ((lane >> 4) << 3));
  };
  auto packstore = [&](unsigned short* dst, int mrow0, int jbase){
    int r = tid >> 4, ch = tid & 15;
    float4 v = *(const float4*)&sOut[r * 64 + ch * 4];
    u64 pk = (u64)(unsigned short)f2bf(v.x)
           | ((u64)(unsigned short)f2bf(v.y) << 16)
           | ((u64)(unsigned short)f2bf(v.z) << 32)
           | ((u64)(unsigned short)f2bf(v.w) << 48);
    ast64((u64*)(dst + (size_t)(mrow0 + r) * 512 + jbase + ch * 4), pk);
  };
  auto attention = [&](int b, float maskv, const float (&w8)[8]){
    float q0 = 0.f, q1 = 0.f;
    #pragma unroll
    for (int cgi = 0; cgi < 8; ++cgi){
      u64 v = ald64((const u64*)(a.qpart + (size_t)(cgi * 64 + b) * 512) + tid);
      union { u64 u; float f[2]; } cv; cv.u = v;
      q0 += cv.f[0]; q1 += cv.f[1];
    }
    qs[2 * tid] = q0; qs[2 * tid + 1] = q1;
    __syncthreads();
    float q8[8];
    #pragma unroll
    for (int j = 0; j < 8; ++j) q8[j] = qs[lane * 8 + j];
    for (int i = 0; i < 16; ++i){
      int s = (wv << 4) + i;
      bf16x8 c8 = *(const bf16x8*)(a.ctx_proj + (size_t)((s << 6) + b) * 512 + lane * 8);
      float p = 0.f;
      #pragma unroll
      for (int j = 0; j < 8; ++j)
        p += ftanh(bf2f(c8[j]) + q8[j]) * w8[j];
      pl[s * 65 + lane] = p;
    }
    __syncthreads();
    if (tid < 64){
      const float* row = pl + tid * 65;
      float v0 = 0.f, v1 = 0.f, v2 = 0.f, v3 = 0.f;
      #pragma unroll
      for (int j = 0; j < 64; j += 4){
        v0 += row[j]; v1 += row[j + 1]; v2 += row[j + 2]; v3 += row[j + 3];
      }
      float v = (v0 + v1) + (v2 + v3);
      v = (maskv > 0.f) ? v : -100000000.0f;
      float mx = v;
      #pragma unroll
      for (int m = 32; m > 0; m >>= 1) mx = fmaxf(mx, __shfl_xor(mx, m, 64));
      float e = __expf(v - mx);
      float se = e;
      #pragma unroll
      for (int m = 32; m > 0; m >>= 1) se += __shfl_xor(se, m, 64);
      al[tid] = e / se;
    }
    __syncthreads();
    float s0 = 0.f, s1 = 0.f;
    int c0 = tid * 2;
    for (int s = 0; s < 64; ++s){
      float2 cv = *(const float2*)(a.ctx + (size_t)((s << 6) + b) * 512 + c0);
      s0 += al[s] * cv.x; s1 += al[s] * cv.y;
    }
    u32 pk = (u32)(unsigned short)f2bf(s0) | ((u32)(unsigned short)f2bf(s1) << 16);
    ast32((u32*)a.catt_bf + (size_t)b * 256 + tid, pk);
  };

  if (wg < 32){
    // ---- Group A: P0 (gru0 + split-K q partials), then attention b=wg ----
    const int rg = wg >> 3, cg = wg & 7;
    const int mrow0 = rg << 4, jbase = cg << 6;
    const int j0 = jbase + (wv << 4);
    const int col = j0 + (lane & 15), lcol = col - jbase;
    const int lr0 = (lane >> 4) << 2;
    const int batt = wg;
    const int abase = (batt >> 4) << 3;
    const float bh0r = a.bhh0[col], bh0z = a.bhh0[512 + col], bh0n = a.bhh0[1024 + col];
    float w8[8];
    #pragma unroll
    for (int j = 0; j < 8; ++j) w8[j] = a.wmlp[lane * 8 + j];
    const float maskv = (tid < 64) ? a.mask[(tid << 6) + batt] : 0.f;
    float g0[4], g1[4], g2[4];
    {
      const float* gi = a.gi0;
      #pragma unroll
      for (int r = 0; r < 4; ++r){
        const float* gib = gi + (size_t)(mrow0 + lr0 + r) * 1536;
        g0[r] = gib[col]; g1[r] = gib[512 + col]; g2[r] = gib[1024 + col];
      }
    }
    #pragma unroll 1
    for (int t = 0; t < 48; ++t){
      const u32 tok = t + 1;
      waitslots<1>(a.barD, rg << 3, 8, (u32)t);
      burst16(a.h_bf, mrow0);
      f32x4 aR = {0,0,0,0}, aZ = {0,0,0,0}, aN = {0,0,0,0};
      for (int k0 = 0; k0 < 512; k0 += 32){
        bf16x8 af = afrag(k0);
        aR = mfma16(af, ldb(a.Whh0, j0,        k0, lane), aR);
        aZ = mfma16(af, ldb(a.Whh0, 512 + j0,  k0, lane), aZ);
        aN = mfma16(af, ldb(a.Whh0, 1024 + j0, k0, lane), aN);
      }
      #pragma unroll
      for (int r = 0; r < 4; ++r){
        int lr = lr0 + r;
        float rr = sigm(g0[r] + aR[r] + bh0r);
        float zz = sigm(g1[r] + aZ[r] + bh0z);
        float nn = ftanh(g2[r] + rr * (aN[r] + bh0n));
        float hp = bf2f((short)sH[lr * 520 + col]);
        sOut[lr * 64 + lcol] = (1.f - zz) * nn + zz * hp;
      }
      __syncthreads();
      packstore(a.h1_bf, mrow0, jbase);
      bf16x8 qa0, qa1;
      #pragma unroll
      for (int j = 0; j < 8; ++j){
        qa0[j] = f2bf(sOut[(lane & 15) * 64 +      ((lane >> 4) << 3) + j]);
        qa1[j] = f2bf(sOut[(lane & 15) * 64 + 32 + ((lane >> 4) << 3) + j]);
      }
      #pragma unroll
      for (int nt = 0; nt < 8; ++nt){
        int n0 = (wv << 7) + (nt << 4);
        f32x4 qacc = {0,0,0,0};
        qacc = mfma16(qa0, ldb(a.Whid2ctx, n0, jbase,      lane), qacc);
        qacc = mfma16(qa1, ldb(a.Whid2ctx, n0, jbase + 32, lane), qacc);
        int qcol = n0 + (lane & 15);
        #pragma unroll
        for (int r = 0; r < 4; ++r)
          astf(a.qpart + (size_t)(cg * 64 + mrow0 + lr0 + r) * 512 + qcol, qacc[r]);
      }
      __syncthreads();
      sig(a.barA, wg, tok);
      waitslots<1>(a.barA, abase, 8, tok);
      attention(batt, maskv, w8);
      __syncthreads();
      sig(a.barC, batt, tok);
      if (t < 47){
        const float* gi = a.gi0 + (size_t)(t + 1) * 98304;
        #pragma unroll
        for (int r = 0; r < 4; ++r){
          const float* gib = gi + (size_t)(mrow0 + lr0 + r) * 1536;
          g0[r] = gib[col]; g1[r] = gib[512 + col]; g2[r] = gib[1024 + col];
        }
      }
    }
  } else if (wg < 64){
    // ---- Group B: gh1 in registers, then P3 -> h_bf + h2bf[t] ----
    const int g = wg - 32;
    const int rg = g >> 3, cg = g & 7;
    const int mrow0 = rg << 4, jbase = cg << 6;
    const int j0 = jbase + (wv << 4);
    const int col = j0 + (lane & 15), lcol = col - jbase;
    const int lr0 = (lane >> 4) << 2;
    const float bcR = a.bih1[col]        + a.bhh1[col];
    const float bcZ = a.bih1[512 + col]  + a.bhh1[512 + col];
    const float biN = a.bih1[1024 + col];
    const float bhN = a.bhh1[1024 + col];
    #pragma unroll 1
    for (int t = 0; t < 48; ++t){
      const u32 tok = t + 1;
      waitslots<1>(a.barA, rg << 3, 8, tok);
      burst16(a.h1_bf, mrow0);
      f32x4 hR = {0,0,0,0}, hZ = {0,0,0,0}, hN = {0,0,0,0};
      for (int k0 = 0; k0 < 512; k0 += 32){
        bf16x8 af = afrag(k0);
        hR = mfma16(af, ldb(a.Whh1, j0,        k0, lane), hR);
        hZ = mfma16(af, ldb(a.Whh1, 512 + j0,  k0, lane), hZ);
        hN = mfma16(af, ldb(a.Whh1, 1024 + j0, k0, lane), hN);
      }
      float hp4[4];
      #pragma unroll
      for (int r = 0; r < 4; ++r) hp4[r] = bf2f((short)sH[(lr0 + r) * 520 + col]);
      waitslots<1>(a.barC, mrow0, 16, tok);
      burst16(a.catt_bf, mrow0);
      f32x4 iR = {0,0,0,0}, iZ = {0,0,0,0}, iN = {0,0,0,0};
      for (int k0 = 0; k0 < 512; k0 += 32){
        bf16x8 af = afrag(k0);
        iR = mfma16(af, ldb(a.Wcomb, j0,        k0, lane), iR);
        iZ = mfma16(af, ldb(a.Wcomb, 512 + j0,  k0, lane), iZ);
        iN = mfma16(af, ldb(a.Wcomb, 1024 + j0, k0, lane), iN);
      }
      #pragma unroll
      for (int r = 0; r < 4; ++r){
        int lr = lr0 + r;
        float rr = sigm(iR[r] + hR[r] + bcR);
        float zz = sigm(iZ[r] + hZ[r] + bcZ);
        float nn = ftanh(iN[r] + biN + rr * (hN[r] + bhN));
        sOut[lr * 64 + lcol] = (1.f - zz) * nn + zz * hp4[r];
      }
      __syncthreads();
      packstore(a.h_bf, mrow0, jbase);
      packstore(a.h2bf + (size_t)t * 32768, mrow0, jbase);
      __syncthreads();
      sig(a.barD, g, tok);
    }
  } else if (wg < 96){
    // ---- Group C: attention for b = 32..63 ----
    const int b = wg - 32;
    const int abase = (b >> 4) << 3;
    float w8[8];
    #pragma unroll
    for (int j = 0; j < 8; ++j) w8[j] = a.wmlp[lane * 8 + j];
    const float maskv = (tid < 64) ? a.mask[(tid << 6) + b] : 0.f;
    #pragma unroll 1
    for (int t = 0; t < 48; ++t){
      const u32 tok = t + 1;
      waitslots<1>(a.barA, abase, 8, tok);
      attention(b, maskv, w8);
      __syncthreads();
      sig(a.barC, b, tok);
    }
  } else if (wg < 128){
    // ---- Group V-L: logits tl(t) = tanh(h2bf[t] @ Whid2out^T + b) ----
    const int vl = wg - 96;
    const int rg = vl >> 3, cg = vl & 7;
    const int mrow0 = rg << 4, jbase = cg << 6;
    const int j0 = jbase + (wv << 4);
    const int col = j0 + (lane & 15), lcol = col - jbase;
    const int lr0 = (lane >> 4) << 2;
    const float bo = a.bh2o[col];
    #pragma unroll 1
    for (int t = 0; t < 48; ++t){
      const u32 tok = t + 1;
      // only our row-group's 8 B producers matter for h2bf rows mrow0..mrow0+16
      waitslots<16>(a.barD, rg << 3, 8, tok);
      const unsigned short* h2t = a.h2bf + (size_t)t * 32768;
      f32x4 acc = {0,0,0,0};
      for (int k0 = 0; k0 < 512; k0 += 32)
        acc = mfma16(ldb_ald(h2t, mrow0, k0, lane), ldb(a.Whid2out, j0, k0, lane), acc);
      #pragma unroll
      for (int r = 0; r < 4; ++r){
        float v = ftanh(acc[r] + bo);
        int row = (t << 6) + mrow0 + lr0 + r;
        a.tl_f[(size_t)row * 512 + col] = v;     // plain store (consumed post-kernel)
        sOut[(lr0 + r) * 64 + lcol] = v;
      }
      __syncthreads();
      packstore(a.tl_bf + (size_t)t * 32768, mrow0, jbase);
      __syncthreads();
      sig(a.barE, vl, tok);
    }
  } else {
    // ---- Group V-G: vocab sumexp; 125 chunks of 256 vocab rows strided by 96 ----
    const int vg = wg - 128;            // 0..95
    // prologue: convert our chunks of W_out2prob fp32->bf16 (disjoint per WG)
    for (int c = vg; c < 125; c += 96){
      const float* src = a.o2p_src + (size_t)c * 256 * 512;
      short* dst = a.o2p_bf + (size_t)c * 256 * 512;
      for (int i = tid; i < 32768; i += 256){
        float4 v = ((const float4*)src)[i];
        s16x4 o; o[0] = f2bf(v.x); o[1] = f2bf(v.y); o[2] = f2bf(v.z); o[3] = f2bf(v.w);
        ((s16x4*)dst)[i] = o;
      }
    }
    __syncthreads();
    #pragma unroll 1
    for (int t = 0; t < 48; ++t){
      const u32 tok = t + 1;
      waitslots<16>(a.barE, 0, 32, tok);
      const unsigned short* tlt = a.tl_bf + (size_t)t * 32768;
      #pragma unroll 1
      for (int c = vg; c < 125; c += 96){
        const int nwave = c * 256 + wv * 64;
        float bos[4];
        #pragma unroll
        for (int ni = 0; ni < 4; ++ni) bos[ni] = a.bop[nwave + ni * 16 + (lane & 15)];
        f32x4 acc[4][4];
        #pragma unroll
        for (int i = 0; i < 4; ++i)
          #pragma unroll
          for (int j = 0; j < 4; ++j) acc[i][j] = (f32x4){0.f, 0.f, 0.f, 0.f};
        for (int k0 = 0; k0 < 512; k0 += 32){
          bf16x8 af[4], bw[4];
          #pragma unroll
          for (int mi = 0; mi < 4; ++mi) af[mi] = ldb_ald(tlt, mi << 4, k0, lane);
          #pragma unroll
          for (int ni = 0; ni < 4; ++ni) bw[ni] = ldb(a.o2p_bf, nwave + (ni << 4), k0, lane);
          #pragma unroll
          for (int mi = 0; mi < 4; ++mi)
            #pragma unroll
            for (int ni = 0; ni < 4; ++ni)
              acc[mi][ni] = mfma16(af[mi], bw[ni], acc[mi][ni]);
        }
        #pragma unroll
        for (int mi = 0; mi < 4; ++mi){
          #pragma unroll
          for (int r = 0; r < 4; ++r){
            float e = 0.f;
            #pragma unroll
            for (int ni = 0; ni < 4; ++ni)
              e += __expf(acc[mi][ni][r] + bos[ni]);
            e += __shfl_xor(e, 1, 64); e += __shfl_xor(e, 2, 64);
            e += __shfl_xor(e, 4, 64); e += __shfl_xor(e, 8, 64);
            if ((lane & 15) == 0)
              atomicAdd(&a.sumexp[(t << 6) + (mi << 4) + ((lane >> 4) << 2) + r], e);
          }
        }
      }
    }
  }
}

// ---------------- post kernels ----------------

__global__ __launch_bounds__(256) void k_loss(const float* __restrict__ tlf, const float* __restrict__ Wop,
                                              const float* __restrict__ bop, const int* __restrict__ y,
                                              const float* __restrict__ sumexp, float* __restrict__ loss){
  int step = blockIdx.x;
  int w = threadIdx.x >> 6, lane = threadIdx.x & 63;
  __shared__ float accw[4];
  float part = 0.f;
  for (int b = w; b < 64; b += 4){
    int row = step * 64 + b;
    int t = y[(step + 1) * 64 + b];
    if (t != 0){
      const float* a = tlf + (size_t)row * 512 + lane * 8;
      const float* wr = Wop + (size_t)t * 512 + lane * 8;
      float d = 0.f;
      #pragma unroll
      for (int j = 0; j < 8; ++j) d += a[j] * wr[j];
      d = wsum(d);
      if (lane == 0) part += d + bop[t] - __logf(sumexp[row]);
    }
  }
  if (lane == 0) accw[w] = part;
  __syncthreads();
  if (threadIdx.x == 0) atomicAdd(loss, -(accw[0] + accw[1] + accw[2] + accw[3]));
}

__global__ void k_final(const float* __restrict__ loss, float* __restrict__ out){
  if (threadIdx.x == 0 && blockIdx.x == 0) out[0] = loss[0];
}

// ---------------- host launch ----------------

extern "C" void kernel_launch(void* const* d_in, const int* in_sizes, int n_in,
                              void* d_out, int out_size, void* d_ws, size_t ws_size,
                              hipStream_t stream) {
  const float* ctx       = (const float*)d_in[0];
  const float* ctx_mask  = (const float*)d_in[1];
  const float* txt_ctx   = (const float*)d_in[2];
  const int*   y         = (const int*)d_in[3];
  const float* emb       = (const float*)d_in[4];
  const float* W_ctx2ctx = (const float*)d_in[5];
  const float* W_hid2ctx = (const float*)d_in[6];
  const float* w_mlp     = (const float*)d_in[7];
  const float* W_ctx2hid = (const float*)d_in[8];
  const float* W_dec_init= (const float*)d_in[9];
  const float* W_ih0     = (const float*)d_in[10];
  const float* W_hh0     = (const float*)d_in[11];
  const float* b_ih0     = (const float*)d_in[12];
  const float* b_hh0     = (const float*)d_in[13];
  const float* W_ih1     = (const float*)d_in[14];
  const float* W_hh1     = (const float*)d_in[15];
  const float* b_ih1     = (const float*)d_in[16];
  const float* b_hh1     = (const float*)d_in[17];
  const float* W_hid2out = (const float*)d_in[18];
  const float* b_hid2out = (const float*)d_in[19];
  const float* W_out2prob= (const float*)d_in[20];
  const float* b_out2prob= (const float*)d_in[21];
  float* out = (float*)d_out;

  char* p = (char*)d_ws;
  auto alloc = [&](size_t n){ char* r = p; p += (n + 255) & ~(size_t)255; return r; };
  short* Wb_hh0     = (short*)alloc((size_t)1536 * 512 * 2);
  short* Wb_hid2ctx = (short*)alloc((size_t)512 * 512 * 2);
  short* Wb_hh1     = (short*)alloc((size_t)1536 * 512 * 2);
  short* Wb_hid2out = (short*)alloc((size_t)512 * 512 * 2);
  short* Wb_dec     = (short*)alloc((size_t)512 * 512 * 2);
  short* Wb_c2c     = (short*)alloc((size_t)512 * 512 * 2);
  short* Wb_ih0     = (short*)alloc((size_t)1536 * 512 * 2);
  short* Wb_o2p     = (short*)alloc((size_t)32000 * 512 * 2);
  short* WctT       = (short*)alloc((size_t)512 * 512 * 2);
  short* Wb_comb    = (short*)alloc((size_t)1536 * 512 * 2);
  short* ctx_projbf = (short*)alloc((size_t)4096 * 512 * 2);
  float* gi0_all    = (float*)alloc((size_t)3072 * 1536 * 4);
  float* mixed      = (float*)alloc((size_t)64 * 512 * 4);
  float* h0buf      = (float*)alloc((size_t)64 * 512 * 4);
  unsigned short* h_bf    = (unsigned short*)alloc((size_t)64 * 512 * 2);
  unsigned short* h1_bf   = (unsigned short*)alloc((size_t)64 * 512 * 2);
  unsigned short* catt_bf = (unsigned short*)alloc((size_t)64 * 512 * 2);
  float* qpart      = (float*)alloc((size_t)8 * 64 * 512 * 4);
  unsigned short* h2bf = (unsigned short*)alloc((size_t)3072 * 512 * 2);
  unsigned short* tl_bf = (unsigned short*)alloc((size_t)3072 * 512 * 2);
  float* tl_f       = (float*)alloc((size_t)3072 * 512 * 4);
  // zero region: sumexp(3072) + loss(1) + 4 barrier arrays (64*SLOT each)
  int nbar = 4 * 64 * SLOT;
  float* zreg       = (float*)alloc((size_t)(3073 + nbar) * 4);
  float* sumexp     = zreg;
  float* lossbuf    = zreg + 3072;
  u32* barA         = (u32*)(zreg + 3073);
  u32* barC         = barA + 64 * SLOT;
  u32* barD         = barC + 64 * SLOT;
  u32* barE         = barD + 64 * SLOT;

  dim3 blk(256);
  // ---- phase 0 (vocab conversion moved into the persistent kernel) ----
  CvtJobs jb;
  const float* srcs[8] = {W_hh0, W_hid2ctx, W_hh1, W_hid2out, W_dec_init, W_ctx2ctx, W_ih0, W_hh0};
  short* dsts[8] = {Wb_hh0, Wb_hid2ctx, Wb_hh1, Wb_hid2out, Wb_dec, Wb_c2c, Wb_ih0, Wb_hh0};
  int sizes4[8] = {1536*512/4, 512*512/4, 1536*512/4, 512*512/4, 512*512/4, 512*512/4, 1536*512/4, 0};
  int cum = 0;
  for (int i = 0; i < 8; ++i){ jb.src[i] = srcs[i]; jb.dst[i] = dsts[i]; jb.cum4[i] = cum; cum += sizes4[i]; }
  jb.cum4[8] = cum;
  k_cvt_multi<<<dim3((cum + 255) / 256), blk, 0, stream>>>(jb, cum);
  k_tc<<<dim3(1024), blk, 0, stream>>>(W_ctx2hid, WctT);
  k_gemm_bt_obf<<<dim3(768), blk, 0, stream>>>(W_ih1, WctT, Wb_comb, 512);       // W_comb 1536x512
  k_meanmix<<<dim3(128), blk, 0, stream>>>(ctx, ctx_mask, txt_ctx, mixed);
  k_gemm_bt<<<dim3(32), blk, 0, stream>>>(mixed, Wb_dec, h0buf, 512, 1);         // h0 = tanh(.)
  k_pack_h0<<<dim3(64), blk, 0, stream>>>(h0buf, (u32*)h_bf);
  k_gemm_bt_obf<<<dim3(2048), blk, 0, stream>>>(ctx, Wb_c2c, ctx_projbf, 512);   // ctx_proj bf16
  k_gi0<<<dim3(4608), blk, 0, stream>>>(y, emb, Wb_ih0, b_ih0, gi0_all);
  k_zero<<<dim3((3073 + nbar + 255) / 256), blk, 0, stream>>>(zreg, 3073 + nbar);
  // defensive zero-init of V-path buffers (finite diagnostics if anything fails)
  k_zero<<<dim3(3072), blk, 0, stream>>>((float*)h2bf, 786432);
  k_zero<<<dim3(3072), blk, 0, stream>>>((float*)tl_bf, 786432);
  k_zero<<<dim3(6144), blk, 0, stream>>>(tl_f, 1572864);

  // ---- phase 1+2 fused: persistent kernel (224 WGs, NORMAL launch) ----
  // __launch_bounds__(256,1) guarantees >=1 block/CU => 224 blocks always
  // co-resident on 256 CUs; kernel uses only flag handshakes (no grid sync).
  RB rb;
  rb.gi0 = gi0_all;
  rb.Whh0 = Wb_hh0; rb.bhh0 = b_hh0;
  rb.Whid2ctx = Wb_hid2ctx;
  rb.Whh1 = Wb_hh1; rb.bhh1 = b_hh1;
  rb.Wcomb = Wb_comb; rb.bih1 = b_ih1;
  rb.ctx_proj = ctx_projbf; rb.ctx = ctx; rb.mask = ctx_mask; rb.wmlp = w_mlp;
  rb.h_bf = h_bf; rb.h1_bf = h1_bf; rb.catt_bf = catt_bf;
  rb.qpart = qpart; rb.h2bf = h2bf;
  rb.Whid2out = Wb_hid2out; rb.bh2o = b_hid2out;
  rb.o2p_src = W_out2prob; rb.o2p_bf = Wb_o2p; rb.bop = b_out2prob;
  rb.tl_bf = tl_bf; rb.tl_f = tl_f; rb.sumexp = sumexp;
  rb.barA = barA; rb.barC = barC; rb.barD = barD; rb.barE = barE;
  k_recur<<<dim3(224), blk, 0, stream>>>(rb);

  // ---- tail ----
  k_loss<<<dim3(48), blk, 0, stream>>>(tl_f, W_out2prob, b_out2prob, y, sumexp, lossbuf);
  k_final<<<dim3(1), blk, 0, stream>>>(lossbuf, out);
}

// Round 7
// 3792.291 us; speedup vs baseline: 1.2545x; 1.2545x over previous
//
#include <hip/hip_runtime.h>
#include <stdint.h>

// S=64, B=64, C=H=E=512, V=32000, steps T=48
// ONE persistent kernel (224 WGs, NORMAL launch; __launch_bounds__(256,1) =>
// >=1 block/CU => all 224 blocks co-resident; flag handshakes only):
//   Group A (WG 0-31):   P0: gru0 -> h1 (bf16) + split-K q-partials, then attention b=wg
//   Group B (WG 32-63):  gh1 in registers, then P3: gi1+combine -> h_bf + h2bf[t]
//   Group C (WG 64-95):  attention for b=32..63
//   Group V-L (96-127):  per step: tl(t) = tanh(h2bf[t]@Whid2out^T + b) -> tl_f, tl_bf
//   Group V-G (128-223): STEP-PAIR batched vocab sumexp (round-5 verified register
//                        pattern, acc[8][4]): wait 2 steps, stream each B-chunk once
//                        against both logit matrices -> vocab traffic halved.
// Vocab bf16 conversion in prep (k_cvt_multi, verified rounds 0-2).
// Sync: scattered per-WG token slots; recurrence polls s_sleep(1), V polls s_sleep(16).

using bf16x8 = __attribute__((ext_vector_type(8))) short;
using f32x4  = __attribute__((ext_vector_type(4))) float;
using s16x4  = __attribute__((ext_vector_type(4))) short;
typedef unsigned long long u64;
typedef unsigned int u32;

#define DI __device__ __forceinline__

DI short f2bf(float x){
  union { float f; uint32_t u; } v; v.f = x;
  uint32_t r = (v.u + 0x7FFFu + ((v.u >> 16) & 1u)) >> 16;
  return (short)r;
}
DI float bf2f(short s){
  union { uint32_t u; float f; } v; v.u = ((uint32_t)(unsigned short)s) << 16; return v.f;
}
DI float sigm(float x){ return __fdividef(1.f, 1.f + __expf(-x)); }
DI float ftanh(float x){ return 1.f - __fdividef(2.f, __expf(2.f*x) + 1.f); }
DI float wsum(float v){
  #pragma unroll
  for (int m = 32; m > 0; m >>= 1) v += __shfl_xor(v, m, 64);
  return v;
}
DI f32x4 mfma16(bf16x8 a, bf16x8 b, f32x4 c){
  return __builtin_amdgcn_mfma_f32_16x16x32_bf16(a, b, c, 0, 0, 0);
}

// AGENT-scope atomics (reach/observe coherence point; no local stale copies)
DI u32  ald32(const u32* p){ return __hip_atomic_load(p, __ATOMIC_RELAXED, __HIP_MEMORY_SCOPE_AGENT); }
DI void ast32(u32* p, u32 v){ __hip_atomic_store(p, v, __ATOMIC_RELAXED, __HIP_MEMORY_SCOPE_AGENT); }
DI u64  ald64(const u64* p){ return __hip_atomic_load(p, __ATOMIC_RELAXED, __HIP_MEMORY_SCOPE_AGENT); }
DI void ast64(u64* p, u64 v){ __hip_atomic_store(p, v, __ATOMIC_RELAXED, __HIP_MEMORY_SCOPE_AGENT); }
DI float aldf(const float* p){ return __hip_atomic_load(p, __ATOMIC_RELAXED, __HIP_MEMORY_SCOPE_AGENT); }
DI void astf(float* p, float v){ __hip_atomic_store(p, v, __ATOMIC_RELAXED, __HIP_MEMORY_SCOPE_AGENT); }

// plain bf16 weight fragment (row-major [N][512])
DI bf16x8 ldb(const short* __restrict__ W, int n0, int k0, int lane){
  return *(const bf16x8*)(W + (size_t)(n0 + (lane & 15)) * 512 + k0 + ((lane >> 4) << 3));
}
// agent-scope bf16 fragment (cross-XCD payloads: h2bf, tl_bf)
DI bf16x8 ldb_ald(const unsigned short* W, int n0, int k0, int lane){
  const u64* p = (const u64*)(W + (size_t)(n0 + (lane & 15)) * 512 + k0 + ((lane >> 4) << 3));
  union { u64 u[2]; bf16x8 f; } cv;
  cv.u[0] = ald64(p); cv.u[1] = ald64(p + 1);
  return cv.f;
}

#define SLOT 64   // dwords per token slot (256 B padding)

// signal: call AFTER __syncthreads() (compiler drains vmcnt before s_barrier)
DI void sig(u32* arr, int slot, u32 tok){
  if (threadIdx.x == 0){
    __builtin_amdgcn_s_waitcnt(0);
    ast32(arr + slot * SLOT, tok);
  }
}
// wait: lane i (<cnt) polls slot base+i; all-ballot; then block barrier
template<int SLP>
DI void waitslots(const u32* arr, int base, int cnt, u32 tok){
  if (threadIdx.x < 64){
    for (;;){
      u32 v = (threadIdx.x < cnt) ? ald32(arr + (base + threadIdx.x) * SLOT) : tok;
      if (__all((int)(v - tok) >= 0)) break;
      __builtin_amdgcn_s_sleep(SLP);
    }
  }
  __syncthreads();
}

// ---------------- elementwise / prep kernels ----------------

struct CvtJobs { const float* src[8]; short* dst[8]; int cum4[9]; };

__global__ __launch_bounds__(256) void k_cvt_multi(CvtJobs jb, int total4){
  int i = blockIdx.x * 256 + threadIdx.x;
  if (i >= total4) return;
  int j = 0;
  #pragma unroll
  for (int k = 0; k < 8; ++k) if (i >= jb.cum4[k + 1]) j = k + 1;
  int off = i - jb.cum4[j];
  float4 v = ((const float4*)jb.src[j])[off];
  s16x4 o; o[0] = f2bf(v.x); o[1] = f2bf(v.y); o[2] = f2bf(v.z); o[3] = f2bf(v.w);
  ((s16x4*)jb.dst[j])[off] = o;
}

__global__ __launch_bounds__(256) void k_tc(const float* __restrict__ W, short* __restrict__ WT){
  int i = blockIdx.x * 256 + threadIdx.x;
  int c = i >> 9, h = i & 511;
  WT[i] = f2bf(W[h * 512 + c]);
}

__global__ __launch_bounds__(256) void k_zero(float* __restrict__ p, int n){
  int i = blockIdx.x * 256 + threadIdx.x;
  if (i < n) p[i] = 0.f;
}

__global__ __launch_bounds__(256) void k_meanmix(const float* __restrict__ ctx, const float* __restrict__ mask,
                                                 const float* __restrict__ txt, float* __restrict__ mixed){
  int i = blockIdx.x * 256 + threadIdx.x;
  int b = i >> 9, c = i & 511;
  float s = 0.f;
  for (int t = 0; t < 64; ++t) s += ctx[(size_t)(t * 64 + b) * 512 + c];
  float dn = 0.f;
  for (int t = 0; t < 64; ++t) dn += mask[t * 64 + b];
  mixed[i] = 0.5f * (s / dn) + 0.5f * txt[i];
}

// pack h0 fp32 -> bf16 packed
__global__ __launch_bounds__(256) void k_pack_h0(const float* __restrict__ h0, u32* __restrict__ hbf){
  int i = blockIdx.x * 256 + threadIdx.x;   // 0..16383
  u32 lo = (u32)(unsigned short)f2bf(h0[2 * i]);
  u32 hi = (u32)(unsigned short)f2bf(h0[2 * i + 1]);
  hbf[i] = lo | (hi << 16);
}

// ---------------- generic wave-tile GEMMs (K = 512, fp32 A) ----------------

DI bf16x8 load_a32(const float* __restrict__ A, int ld, int m0, int k0, int lane){
  const float* p = A + (size_t)(m0 + (lane & 15)) * ld + k0 + ((lane >> 4) << 3);
  bf16x8 f;
  #pragma unroll
  for (int j = 0; j < 8; ++j) f[j] = f2bf(p[j]);
  return f;
}

__global__ __launch_bounds__(256) void k_gemm_bt(const float* __restrict__ A, const short* __restrict__ W,
                                                 float* __restrict__ C, int N, int act){
  int wg = blockIdx.x * 4 + (threadIdx.x >> 6);
  int lane = threadIdx.x & 63;
  int ntiles = N >> 4;
  int mt = wg / ntiles, nt = wg - mt * ntiles;
  int m0 = mt << 4, n0 = nt << 4;
  f32x4 acc = {0.f, 0.f, 0.f, 0.f};
  for (int k = 0; k < 512; k += 32)
    acc = mfma16(load_a32(A, 512, m0, k, lane), ldb(W, n0, k, lane), acc);
  int col = n0 + (lane & 15);
  int r0 = m0 + ((lane >> 4) << 2);
  #pragma unroll
  for (int r = 0; r < 4; ++r){
    float v = acc[r];
    if (act) v = ftanh(v);
    C[(size_t)(r0 + r) * N + col] = v;
  }
}

__global__ __launch_bounds__(256) void k_gemm_bt_obf(const float* __restrict__ A, const short* __restrict__ W,
                                                     short* __restrict__ C, int N){
  int wg = blockIdx.x * 4 + (threadIdx.x >> 6);
  int lane = threadIdx.x & 63;
  int ntiles = N >> 4;
  int mt = wg / ntiles, nt = wg - mt * ntiles;
  int m0 = mt << 4, n0 = nt << 4;
  f32x4 acc = {0.f, 0.f, 0.f, 0.f};
  for (int k = 0; k < 512; k += 32)
    acc = mfma16(load_a32(A, 512, m0, k, lane), ldb(W, n0, k, lane), acc);
  int col = n0 + (lane & 15);
  int r0 = m0 + ((lane >> 4) << 2);
  #pragma unroll
  for (int r = 0; r < 4; ++r)
    C[(size_t)(r0 + r) * N + col] = f2bf(acc[r]);
}

__global__ __launch_bounds__(256) void k_gi0(const int* __restrict__ y, const float* __restrict__ emb,
                                             const short* __restrict__ W, const float* __restrict__ bias,
                                             float* __restrict__ C){
  int wg = blockIdx.x * 4 + (threadIdx.x >> 6);
  int lane = threadIdx.x & 63;
  int mt = wg / 96, nt = wg - mt * 96;
  int m0 = mt << 4, n0 = nt << 4;
  int yr = y[m0 + (lane & 15)];
  const float* arow = emb + (size_t)yr * 512;
  f32x4 acc = {0.f, 0.f, 0.f, 0.f};
  for (int k = 0; k < 512; k += 32){
    const float* p = arow + k + ((lane >> 4) << 3);
    bf16x8 a;
    #pragma unroll
    for (int j = 0; j < 8; ++j) a[j] = f2bf(p[j]);
    acc = mfma16(a, ldb(W, n0, k, lane), acc);
  }
  int col = n0 + (lane & 15);
  int r0 = m0 + ((lane >> 4) << 2);
  #pragma unroll
  for (int r = 0; r < 4; ++r)
    C[(size_t)(r0 + r) * 1536 + col] = acc[r] + bias[col];
}

// ---------------- persistent kernel ----------------

struct RB {
  const float* gi0;        // [48][64][1536] fp32 (incl b_ih0)
  const short* Whh0; const float* bhh0;
  const short* Whid2ctx;   // bf16 [512][512]
  const short* Whh1; const float* bhh1;
  const short* Wcomb; const float* bih1;
  const short* ctx_proj;   // bf16 [s*64+b][512]
  const float* ctx;        // fp32 [s*64+b][512]
  const float* mask;       // [64][64] (s,b)
  const float* wmlp;       // [512]
  unsigned short* h_bf;    // [64][512] bf16 (recurrent state)
  unsigned short* h1_bf;   // [64][512] bf16
  unsigned short* catt_bf; // [64][512] bf16
  float* qpart;            // [8 cg][64 b][512] fp32 split-K q partials
  unsigned short* h2bf;    // [48][64][512] bf16
  // vocab pipeline
  const short* Whid2out; const float* bh2o;
  const short* o2p_bf;     // bf16 [32000][512] (converted in prep)
  const float* bop;        // [32000]
  unsigned short* tl_bf;   // [48*64][512] bf16
  float* tl_f;             // [48*64][512] fp32
  float* sumexp;           // [3072]
  u32* barA; u32* barC; u32* barD; u32* barE;  // token slots, stride SLOT
};

__global__ __launch_bounds__(256, 1) void k_recur(RB a){
  // sH/sOut (GEMM phases) and pl (attention score partials) overlay the same LDS.
  __shared__ char smem[16 * 520 * 2 + 16 * 64 * 4];
  unsigned short* sH = (unsigned short*)smem;            // [16][520] bf16 burst tile
  float* sOut = (float*)(smem + 16 * 520 * 2);           // [16][64]
  float* pl   = (float*)smem;                            // [64][65] score partials
  __shared__ float qs[512];
  __shared__ float al[64];
  const int wg = blockIdx.x, tid = threadIdx.x;
  const int wv = tid >> 6, lane = tid & 63;

  // burst 16 rows x 512 bf16 into sH
  auto burst16 = [&](const unsigned short* src, int row0){
    #pragma unroll
    for (int i = 0; i < 8; ++i){
      int idx = tid + i * 256;              // 0..2047
      int r = idx >> 7, c4 = idx & 127;     // 128 b64-chunks per row
      u64 v = ald64((const u64*)(src + (size_t)(row0 + r) * 512) + c4);
      *(u64*)(sH + r * 520 + c4 * 4) = v;
    }
    __syncthreads();
  };
  auto afrag = [&](int k0) -> bf16x8 {
    return *(const bf16x8*)(sH + (lane & 15) * 520 + k0 + ((lane >> 4) << 3));
  };
  auto packstore = [&](unsigned short* dst, int mrow0, int jbase){
    int r = tid >> 4, ch = tid & 15;
    float4 v = *(const float4*)&sOut[r * 64 + ch * 4];
    u64 pk = (u64)(unsigned short)f2bf(v.x)
           | ((u64)(unsigned short)f2bf(v.y) << 16)
           | ((u64)(unsigned short)f2bf(v.z) << 32)
           | ((u64)(unsigned short)f2bf(v.w) << 48);
    ast64((u64*)(dst + (size_t)(mrow0 + r) * 512 + jbase + ch * 4), pk);
  };
  auto attention = [&](int b, float maskv, const float (&w8)[8]){
    float q0 = 0.f, q1 = 0.f;
    #pragma unroll
    for (int cgi = 0; cgi < 8; ++cgi){
      u64 v = ald64((const u64*)(a.qpart + (size_t)(cgi * 64 + b) * 512) + tid);
      union { u64 u; float f[2]; } cv; cv.u = v;
      q0 += cv.f[0]; q1 += cv.f[1];
    }
    qs[2 * tid] = q0; qs[2 * tid + 1] = q1;
    __syncthreads();
    float q8[8];
    #pragma unroll
    for (int j = 0; j < 8; ++j) q8[j] = qs[lane * 8 + j];
    for (int i = 0; i < 16; ++i){
      int s = (wv << 4) + i;
      bf16x8 c8 = *(const bf16x8*)(a.ctx_proj + (size_t)((s << 6) + b) * 512 + lane * 8);
      float p = 0.f;
      #pragma unroll
      for (int j = 0; j < 8; ++j)
        p += ftanh(bf2f(c8[j]) + q8[j]) * w8[j];
      pl[s * 65 + lane] = p;
    }
    __syncthreads();
    if (tid < 64){
      const float* row = pl + tid * 65;
      float v0 = 0.f, v1 = 0.f, v2 = 0.f, v3 = 0.f;
      #pragma unroll
      for (int j = 0; j < 64; j += 4){
        v0 += row[j]; v1 += row[j + 1]; v2 += row[j + 2]; v3 += row[j + 3];
      }
      float v = (v0 + v1) + (v2 + v3);
      v = (maskv > 0.f) ? v : -100000000.0f;
      float mx = v;
      #pragma unroll
      for (int m = 32; m > 0; m >>= 1) mx = fmaxf(mx, __shfl_xor(mx, m, 64));
      float e = __expf(v - mx);
      float se = e;
      #pragma unroll
      for (int m = 32; m > 0; m >>= 1) se += __shfl_xor(se, m, 64);
      al[tid] = e / se;
    }
    __syncthreads();
    float s0 = 0.f, s1 = 0.f;
    int c0 = tid * 2;
    for (int s = 0; s < 64; ++s){
      float2 cv = *(const float2*)(a.ctx + (size_t)((s << 6) + b) * 512 + c0);
      s0 += al[s] * cv.x; s1 += al[s] * cv.y;
    }
    u32 pk = (u32)(unsigned short)f2bf(s0) | ((u32)(unsigned short)f2bf(s1) << 16);
    ast32((u32*)a.catt_bf + (size_t)b * 256 + tid, pk);
  };

  if (wg < 32){
    // ---- Group A: P0 (gru0 + split-K q partials), then attention b=wg ----
    const int rg = wg >> 3, cg = wg & 7;
    const int mrow0 = rg << 4, jbase = cg << 6;
    const int j0 = jbase + (wv << 4);
    const int col = j0 + (lane & 15), lcol = col - jbase;
    const int lr0 = (lane >> 4) << 2;
    const int batt = wg;
    const int abase = (batt >> 4) << 3;
    const float bh0r = a.bhh0[col], bh0z = a.bhh0[512 + col], bh0n = a.bhh0[1024 + col];
    float w8[8];
    #pragma unroll
    for (int j = 0; j < 8; ++j) w8[j] = a.wmlp[lane * 8 + j];
    const float maskv = (tid < 64) ? a.mask[(tid << 6) + batt] : 0.f;
    float g0[4], g1[4], g2[4];
    {
      const float* gi = a.gi0;
      #pragma unroll
      for (int r = 0; r < 4; ++r){
        const float* gib = gi + (size_t)(mrow0 + lr0 + r) * 1536;
        g0[r] = gib[col]; g1[r] = gib[512 + col]; g2[r] = gib[1024 + col];
      }
    }
    #pragma unroll 1
    for (int t = 0; t < 48; ++t){
      const u32 tok = t + 1;
      waitslots<1>(a.barD, rg << 3, 8, (u32)t);
      burst16(a.h_bf, mrow0);
      f32x4 aR = {0,0,0,0}, aZ = {0,0,0,0}, aN = {0,0,0,0};
      for (int k0 = 0; k0 < 512; k0 += 32){
        bf16x8 af = afrag(k0);
        aR = mfma16(af, ldb(a.Whh0, j0,        k0, lane), aR);
        aZ = mfma16(af, ldb(a.Whh0, 512 + j0,  k0, lane), aZ);
        aN = mfma16(af, ldb(a.Whh0, 1024 + j0, k0, lane), aN);
      }
      #pragma unroll
      for (int r = 0; r < 4; ++r){
        int lr = lr0 + r;
        float rr = sigm(g0[r] + aR[r] + bh0r);
        float zz = sigm(g1[r] + aZ[r] + bh0z);
        float nn = ftanh(g2[r] + rr * (aN[r] + bh0n));
        float hp = bf2f((short)sH[lr * 520 + col]);
        sOut[lr * 64 + lcol] = (1.f - zz) * nn + zz * hp;
      }
      __syncthreads();
      packstore(a.h1_bf, mrow0, jbase);
      bf16x8 qa0, qa1;
      #pragma unroll
      for (int j = 0; j < 8; ++j){
        qa0[j] = f2bf(sOut[(lane & 15) * 64 +      ((lane >> 4) << 3) + j]);
        qa1[j] = f2bf(sOut[(lane & 15) * 64 + 32 + ((lane >> 4) << 3) + j]);
      }
      #pragma unroll
      for (int nt = 0; nt < 8; ++nt){
        int n0 = (wv << 7) + (nt << 4);
        f32x4 qacc = {0,0,0,0};
        qacc = mfma16(qa0, ldb(a.Whid2ctx, n0, jbase,      lane), qacc);
        qacc = mfma16(qa1, ldb(a.Whid2ctx, n0, jbase + 32, lane), qacc);
        int qcol = n0 + (lane & 15);
        #pragma unroll
        for (int r = 0; r < 4; ++r)
          astf(a.qpart + (size_t)(cg * 64 + mrow0 + lr0 + r) * 512 + qcol, qacc[r]);
      }
      __syncthreads();
      sig(a.barA, wg, tok);
      waitslots<1>(a.barA, abase, 8, tok);
      attention(batt, maskv, w8);
      __syncthreads();
      sig(a.barC, batt, tok);
      if (t < 47){
        const float* gi = a.gi0 + (size_t)(t + 1) * 98304;
        #pragma unroll
        for (int r = 0; r < 4; ++r){
          const float* gib = gi + (size_t)(mrow0 + lr0 + r) * 1536;
          g0[r] = gib[col]; g1[r] = gib[512 + col]; g2[r] = gib[1024 + col];
        }
      }
    }
  } else if (wg < 64){
    // ---- Group B: gh1 in registers, then P3 -> h_bf + h2bf[t] ----
    const int g = wg - 32;
    const int rg = g >> 3, cg = g & 7;
    const int mrow0 = rg << 4, jbase = cg << 6;
    const int j0 = jbase + (wv << 4);
    const int col = j0 + (lane & 15), lcol = col - jbase;
    const int lr0 = (lane >> 4) << 2;
    const float bcR = a.bih1[col]        + a.bhh1[col];
    const float bcZ = a.bih1[512 + col]  + a.bhh1[512 + col];
    const float biN = a.bih1[1024 + col];
    const float bhN = a.bhh1[1024 + col];
    #pragma unroll 1
    for (int t = 0; t < 48; ++t){
      const u32 tok = t + 1;
      waitslots<1>(a.barA, rg << 3, 8, tok);
      burst16(a.h1_bf, mrow0);
      f32x4 hR = {0,0,0,0}, hZ = {0,0,0,0}, hN = {0,0,0,0};
      for (int k0 = 0; k0 < 512; k0 += 32){
        bf16x8 af = afrag(k0);
        hR = mfma16(af, ldb(a.Whh1, j0,        k0, lane), hR);
        hZ = mfma16(af, ldb(a.Whh1, 512 + j0,  k0, lane), hZ);
        hN = mfma16(af, ldb(a.Whh1, 1024 + j0, k0, lane), hN);
      }
      float hp4[4];
      #pragma unroll
      for (int r = 0; r < 4; ++r) hp4[r] = bf2f((short)sH[(lr0 + r) * 520 + col]);
      waitslots<1>(a.barC, mrow0, 16, tok);
      burst16(a.catt_bf, mrow0);
      f32x4 iR = {0,0,0,0}, iZ = {0,0,0,0}, iN = {0,0,0,0};
      for (int k0 = 0; k0 < 512; k0 += 32){
        bf16x8 af = afrag(k0);
        iR = mfma16(af, ldb(a.Wcomb, j0,        k0, lane), iR);
        iZ = mfma16(af, ldb(a.Wcomb, 512 + j0,  k0, lane), iZ);
        iN = mfma16(af, ldb(a.Wcomb, 1024 + j0, k0, lane), iN);
      }
      #pragma unroll
      for (int r = 0; r < 4; ++r){
        int lr = lr0 + r;
        float rr = sigm(iR[r] + hR[r] + bcR);
        float zz = sigm(iZ[r] + hZ[r] + bcZ);
        float nn = ftanh(iN[r] + biN + rr * (hN[r] + bhN));
        sOut[lr * 64 + lcol] = (1.f - zz) * nn + zz * hp4[r];
      }
      __syncthreads();
      packstore(a.h_bf, mrow0, jbase);
      packstore(a.h2bf + (size_t)t * 32768, mrow0, jbase);
      __syncthreads();
      sig(a.barD, g, tok);
    }
  } else if (wg < 96){
    // ---- Group C: attention for b = 32..63 ----
    const int b = wg - 32;
    const int abase = (b >> 4) << 3;
    float w8[8];
    #pragma unroll
    for (int j = 0; j < 8; ++j) w8[j] = a.wmlp[lane * 8 + j];
    const float maskv = (tid < 64) ? a.mask[(tid << 6) + b] : 0.f;
    #pragma unroll 1
    for (int t = 0; t < 48; ++t){
      const u32 tok = t + 1;
      waitslots<1>(a.barA, abase, 8, tok);
      attention(b, maskv, w8);
      __syncthreads();
      sig(a.barC, b, tok);
    }
  } else if (wg < 128){
    // ---- Group V-L: logits tl(t) = tanh(h2bf[t] @ Whid2out^T + b) ----
    const int vl = wg - 96;
    const int rg = vl >> 3, cg = vl & 7;
    const int mrow0 = rg << 4, jbase = cg << 6;
    const int j0 = jbase + (wv << 4);
    const int col = j0 + (lane & 15), lcol = col - jbase;
    const int lr0 = (lane >> 4) << 2;
    const float bo = a.bh2o[col];
    #pragma unroll 1
    for (int t = 0; t < 48; ++t){
      const u32 tok = t + 1;
      // only our row-group's 8 B producers matter for h2bf rows mrow0..mrow0+16
      waitslots<16>(a.barD, rg << 3, 8, tok);
      const unsigned short* h2t = a.h2bf + (size_t)t * 32768;
      f32x4 acc = {0,0,0,0};
      for (int k0 = 0; k0 < 512; k0 += 32)
        acc = mfma16(ldb_ald(h2t, mrow0, k0, lane), ldb(a.Whid2out, j0, k0, lane), acc);
      #pragma unroll
      for (int r = 0; r < 4; ++r){
        float v = ftanh(acc[r] + bo);
        int row = (t << 6) + mrow0 + lr0 + r;
        a.tl_f[(size_t)row * 512 + col] = v;     // plain store (consumed post-kernel)
        sOut[(lr0 + r) * 64 + lcol] = v;
      }
      __syncthreads();
      packstore(a.tl_bf + (size_t)t * 32768, mrow0, jbase);
      __syncthreads();
      sig(a.barE, vl, tok);
    }
  } else {
    // ---- Group V-G: step-pair batched vocab sumexp (register pattern) ----
    const int vg = wg - 128;            // 0..95
    #pragma unroll 1
    for (int p = 0; p < 24; ++p){
      const u32 tok = 2 * p + 2;        // both steps of the pair done
      waitslots<16>(a.barE, 0, 32, tok);
      const unsigned short* tlt = a.tl_bf + (size_t)p * 65536;  // 128 rows (2 steps)
      #pragma unroll 1
      for (int c = vg; c < 125; c += 96){
        const int nwave = c * 256 + wv * 64;
        float bos[4];
        #pragma unroll
        for (int ni = 0; ni < 4; ++ni) bos[ni] = a.bop[nwave + ni * 16 + (lane & 15)];
        f32x4 acc[8][4];
        #pragma unroll
        for (int i = 0; i < 8; ++i)
          #pragma unroll
          for (int j = 0; j < 4; ++j) acc[i][j] = (f32x4){0.f, 0.f, 0.f, 0.f};
        for (int k0 = 0; k0 < 512; k0 += 32){
          bf16x8 af[8], bw[4];
          #pragma unroll
          for (int mi = 0; mi < 8; ++mi) af[mi] = ldb_ald(tlt, mi << 4, k0, lane);
          #pragma unroll
          for (int ni = 0; ni < 4; ++ni) bw[ni] = ldb(a.o2p_bf, nwave + (ni << 4), k0, lane);
          #pragma unroll
          for (int mi = 0; mi < 8; ++mi)
            #pragma unroll
            for (int ni = 0; ni < 4; ++ni)
              acc[mi][ni] = mfma16(af[mi], bw[ni], acc[mi][ni]);
        }
        #pragma unroll
        for (int mi = 0; mi < 8; ++mi){
          const int t = 2 * p + (mi >> 2);
          const int mrow = (mi & 3) << 4;
          #pragma unroll
          for (int r = 0; r < 4; ++r){
            float e = 0.f;
            #pragma unroll
            for (int ni = 0; ni < 4; ++ni)
              e += __expf(acc[mi][ni][r] + bos[ni]);
            e += __shfl_xor(e, 1, 64); e += __shfl_xor(e, 2, 64);
            e += __shfl_xor(e, 4, 64); e += __shfl_xor(e, 8, 64);
            if ((lane & 15) == 0)
              atomicAdd(&a.sumexp[(t << 6) + mrow + ((lane >> 4) << 2) + r], e);
          }
        }
      }
    }
  }
}

// ---------------- post kernels ----------------

__global__ __launch_bounds__(256) void k_loss(const float* __restrict__ tlf, const float* __restrict__ Wop,
                                              const float* __restrict__ bop, const int* __restrict__ y,
                                              const float* __restrict__ sumexp, float* __restrict__ loss){
  int step = blockIdx.x;
  int w = threadIdx.x >> 6, lane = threadIdx.x & 63;
  __shared__ float accw[4];
  float part = 0.f;
  for (int b = w; b < 64; b += 4){
    int row = step * 64 + b;
    int t = y[(step + 1) * 64 + b];
    if (t != 0){
      const float* a = tlf + (size_t)row * 512 + lane * 8;
      const float* wr = Wop + (size_t)t * 512 + lane * 8;
      float d = 0.f;
      #pragma unroll
      for (int j = 0; j < 8; ++j) d += a[j] * wr[j];
      d = wsum(d);
      if (lane == 0) part += d + bop[t] - __logf(sumexp[row]);
    }
  }
  if (lane == 0) accw[w] = part;
  __syncthreads();
  if (threadIdx.x == 0) atomicAdd(loss, -(accw[0] + accw[1] + accw[2] + accw[3]));
}

__global__ void k_final(const float* __restrict__ loss, float* __restrict__ out){
  if (threadIdx.x == 0 && blockIdx.x == 0) out[0] = loss[0];
}

// ---------------- host launch ----------------

extern "C" void kernel_launch(void* const* d_in, const int* in_sizes, int n_in,
                              void* d_out, int out_size, void* d_ws, size_t ws_size,
                              hipStream_t stream) {
  const float* ctx       = (const float*)d_in[0];
  const float* ctx_mask  = (const float*)d_in[1];
  const float* txt_ctx   = (const float*)d_in[2];
  const int*   y         = (const int*)d_in[3];
  const float* emb       = (const float*)d_in[4];
  const float* W_ctx2ctx = (const float*)d_in[5];
  const float* W_hid2ctx = (const float*)d_in[6];
  const float* w_mlp     = (const float*)d_in[7];
  const float* W_ctx2hid = (const float*)d_in[8];
  const float* W_dec_init= (const float*)d_in[9];
  const float* W_ih0     = (const float*)d_in[10];
  const float* W_hh0     = (const float*)d_in[11];
  const float* b_ih0     = (const float*)d_in[12];
  const float* b_hh0     = (const float*)d_in[13];
  const float* W_ih1     = (const float*)d_in[14];
  const float* W_hh1     = (const float*)d_in[15];
  const float* b_ih1     = (const float*)d_in[16];
  const float* b_hh1     = (const float*)d_in[17];
  const float* W_hid2out = (const float*)d_in[18];
  const float* b_hid2out = (const float*)d_in[19];
  const float* W_out2prob= (const float*)d_in[20];
  const float* b_out2prob= (const float*)d_in[21];
  float* out = (float*)d_out;

  char* p = (char*)d_ws;
  auto alloc = [&](size_t n){ char* r = p; p += (n + 255) & ~(size_t)255; return r; };
  short* Wb_hh0     = (short*)alloc((size_t)1536 * 512 * 2);
  short* Wb_hid2ctx = (short*)alloc((size_t)512 * 512 * 2);
  short* Wb_hh1     = (short*)alloc((size_t)1536 * 512 * 2);
  short* Wb_hid2out = (short*)alloc((size_t)512 * 512 * 2);
  short* Wb_dec     = (short*)alloc((size_t)512 * 512 * 2);
  short* Wb_c2c     = (short*)alloc((size_t)512 * 512 * 2);
  short* Wb_ih0     = (short*)alloc((size_t)1536 * 512 * 2);
  short* Wb_o2p     = (short*)alloc((size_t)32000 * 512 * 2);
  short* WctT       = (short*)alloc((size_t)512 * 512 * 2);
  short* Wb_comb    = (short*)alloc((size_t)1536 * 512 * 2);
  short* ctx_projbf = (short*)alloc((size_t)4096 * 512 * 2);
  float* gi0_all    = (float*)alloc((size_t)3072 * 1536 * 4);
  float* mixed      = (float*)alloc((size_t)64 * 512 * 4);
  float* h0buf      = (float*)alloc((size_t)64 * 512 * 4);
  unsigned short* h_bf    = (unsigned short*)alloc((size_t)64 * 512 * 2);
  unsigned short* h1_bf   = (unsigned short*)alloc((size_t)64 * 512 * 2);
  unsigned short* catt_bf = (unsigned short*)alloc((size_t)64 * 512 * 2);
  float* qpart      = (float*)alloc((size_t)8 * 64 * 512 * 4);
  unsigned short* h2bf = (unsigned short*)alloc((size_t)3072 * 512 * 2);
  unsigned short* tl_bf = (unsigned short*)alloc((size_t)3072 * 512 * 2);
  float* tl_f       = (float*)alloc((size_t)3072 * 512 * 4);
  // zero region: sumexp(3072) + loss(1) + 4 barrier arrays (64*SLOT each)
  int nbar = 4 * 64 * SLOT;
  float* zreg       = (float*)alloc((size_t)(3073 + nbar) * 4);
  float* sumexp     = zreg;
  float* lossbuf    = zreg + 3072;
  u32* barA         = (u32*)(zreg + 3073);
  u32* barC         = barA + 64 * SLOT;
  u32* barD         = barC + 64 * SLOT;
  u32* barE         = barD + 64 * SLOT;

  dim3 blk(256);
  // ---- phase 0 (vocab bf16 conversion in prep: full-GPU, verified r0-r2) ----
  CvtJobs jb;
  const float* srcs[8] = {W_hh0, W_hid2ctx, W_hh1, W_hid2out, W_dec_init, W_ctx2ctx, W_ih0, W_out2prob};
  short* dsts[8] = {Wb_hh0, Wb_hid2ctx, Wb_hh1, Wb_hid2out, Wb_dec, Wb_c2c, Wb_ih0, Wb_o2p};
  int sizes4[8] = {1536*512/4, 512*512/4, 1536*512/4, 512*512/4, 512*512/4, 512*512/4, 1536*512/4, 32000*512/4};
  int cum = 0;
  for (int i = 0; i < 8; ++i){ jb.src[i] = srcs[i]; jb.dst[i] = dsts[i]; jb.cum4[i] = cum; cum += sizes4[i]; }
  jb.cum4[8] = cum;
  k_cvt_multi<<<dim3((cum + 255) / 256), blk, 0, stream>>>(jb, cum);
  k_tc<<<dim3(1024), blk, 0, stream>>>(W_ctx2hid, WctT);
  k_gemm_bt_obf<<<dim3(768), blk, 0, stream>>>(W_ih1, WctT, Wb_comb, 512);       // W_comb 1536x512
  k_meanmix<<<dim3(128), blk, 0, stream>>>(ctx, ctx_mask, txt_ctx, mixed);
  k_gemm_bt<<<dim3(32), blk, 0, stream>>>(mixed, Wb_dec, h0buf, 512, 1);         // h0 = tanh(.)
  k_pack_h0<<<dim3(64), blk, 0, stream>>>(h0buf, (u32*)h_bf);
  k_gemm_bt_obf<<<dim3(2048), blk, 0, stream>>>(ctx, Wb_c2c, ctx_projbf, 512);   // ctx_proj bf16
  k_gi0<<<dim3(4608), blk, 0, stream>>>(y, emb, Wb_ih0, b_ih0, gi0_all);
  k_zero<<<dim3((3073 + nbar + 255) / 256), blk, 0, stream>>>(zreg, 3073 + nbar);
  // defensive zero-init of V-path buffers (finite diagnostics if anything fails)
  k_zero<<<dim3(3072), blk, 0, stream>>>((float*)h2bf, 786432);
  k_zero<<<dim3(3072), blk, 0, stream>>>((float*)tl_bf, 786432);
  k_zero<<<dim3(6144), blk, 0, stream>>>(tl_f, 1572864);

  // ---- phase 1+2 fused: persistent kernel (224 WGs, NORMAL launch) ----
  RB rb;
  rb.gi0 = gi0_all;
  rb.Whh0 = Wb_hh0; rb.bhh0 = b_hh0;
  rb.Whid2ctx = Wb_hid2ctx;
  rb.Whh1 = Wb_hh1; rb.bhh1 = b_hh1;
  rb.Wcomb = Wb_comb; rb.bih1 = b_ih1;
  rb.ctx_proj = ctx_projbf; rb.ctx = ctx; rb.mask = ctx_mask; rb.wmlp = w_mlp;
  rb.h_bf = h_bf; rb.h1_bf = h1_bf; rb.catt_bf = catt_bf;
  rb.qpart = qpart; rb.h2bf = h2bf;
  rb.Whid2out = Wb_hid2out; rb.bh2o = b_hid2out;
  rb.o2p_bf = Wb_o2p; rb.bop = b_out2prob;
  rb.tl_bf = tl_bf; rb.tl_f = tl_f; rb.sumexp = sumexp;
  rb.barA = barA; rb.barC = barC; rb.barD = barD; rb.barE = barE;
  k_recur<<<dim3(224), blk, 0, stream>>>(rb);

  // ---- tail ----
  k_loss<<<dim3(48), blk, 0, stream>>>(tl_f, W_out2prob, b_out2prob, y, sumexp, lossbuf);
  k_final<<<dim3(1), blk, 0, stream>>>(lossbuf, out);
}